// Round 1
// baseline (861.887 us; speedup 1.0000x reference)
//
#include <hip/hip_runtime.h>

// Fully-fused 5-layer bidirectional GRU, fp32 VALU.
// Decomposition: 10 lanes per batch element = 2 dirs x 5 hidden units.
// Lane (e,d,j) owns gate rows {j, j+5, j+10} of W_ih/W_hh (kept in VGPRs),
// exchanges h via ds_bpermute each step. 6 elems per 64-lane wave; one wave
// per block (no __syncthreads needed inside layers). Seq buffers ping-pong
// in LDS: [2][T][6 elems][12 ch padded] = 17.3 KB -> 9 waves/CU.

#define NB 262144
#define T 30

__device__ __forceinline__ float fast_sigmoid(float x) {
    float e = __builtin_amdgcn_exp2f(-1.4426950408889634f * x);
    return __builtin_amdgcn_rcpf(1.0f + e);
}
__device__ __forceinline__ float fast_tanh(float x) {
    float u = __builtin_amdgcn_exp2f(2.8853900817779268f * x);
    return fmaf(-2.0f, __builtin_amdgcn_rcpf(1.0f + u), 1.0f);
}

template <int D>
__device__ __forceinline__ void gru_layer(
    const float* __restrict__ wih, const float* __restrict__ whh,
    const float* __restrict__ bih, const float* __restrict__ bhh,
    const float (*bin)[6][12], float (*bout)[6][12],
    int e, int d, int j, int a0, int a1, int a2, int a3, int a4)
{
    // weights for this lane's 3 gate rows (r=j, z=j+5, n=j+10)
    float wi0[D], wi1[D], wi2[D];
    float wh0[5], wh1[5], wh2[5];
#pragma unroll
    for (int k = 0; k < D; k++) {
        wi0[k] = wih[j * D + k];
        wi1[k] = wih[(j + 5) * D + k];
        wi2[k] = wih[(j + 10) * D + k];
    }
#pragma unroll
    for (int k = 0; k < 5; k++) {
        wh0[k] = whh[j * 5 + k];
        wh1[k] = whh[(j + 5) * 5 + k];
        wh2[k] = whh[(j + 10) * 5 + k];
    }
    const float br  = bih[j]      + bhh[j];       // r,z biases combine
    const float bz  = bih[j + 5]  + bhh[j + 5];
    const float bin_ = bih[j + 10];               // n biases must stay split
    const float bhn  = bhh[j + 10];

    float h[5] = {0.f, 0.f, 0.f, 0.f, 0.f};  // full h, gathered (const idx only)
    float hme = 0.f;                          // this lane's own h_j
    const int outc = 5 * d + j;

    for (int t = 0; t < T; t++) {
        const int td = d ? (T - 1 - t) : t;
        const float* xr = &bin[td][e][0];
        float ar = br, az = bz, an = bin_, ah = bhn;
        if (D == 1) {
            float xv = xr[0];
            ar = fmaf(wi0[0], xv, ar);
            az = fmaf(wi1[0], xv, az);
            an = fmaf(wi2[0], xv, an);
        } else {
            float4 xa = *(const float4*)xr;
            float4 xb = *(const float4*)(xr + 4);
            float2 xc = *(const float2*)(xr + 8);
            float xv[10] = {xa.x, xa.y, xa.z, xa.w, xb.x, xb.y, xb.z, xb.w, xc.x, xc.y};
#pragma unroll
            for (int k = 0; k < 10; k++) {
                ar = fmaf(wi0[k], xv[k], ar);
                az = fmaf(wi1[k], xv[k], az);
                an = fmaf(wi2[k], xv[k], an);
            }
        }
#pragma unroll
        for (int k = 0; k < 5; k++) {
            ar = fmaf(wh0[k], h[k], ar);
            az = fmaf(wh1[k], h[k], az);
            ah = fmaf(wh2[k], h[k], ah);
        }
        float r = fast_sigmoid(ar);
        float z = fast_sigmoid(az);
        float n = fast_tanh(fmaf(r, ah, an));
        float hnew = fmaf(z, hme - n, n);   // (1-z)*n + z*h
        hme = hnew;
        bout[td][e][outc] = hnew;
        // gather full h of this (elem, dir) group from lanes Lb..Lb+4
        int hb = __float_as_int(hnew);
        h[0] = __int_as_float(__builtin_amdgcn_ds_bpermute(a0, hb));
        h[1] = __int_as_float(__builtin_amdgcn_ds_bpermute(a1, hb));
        h[2] = __int_as_float(__builtin_amdgcn_ds_bpermute(a2, hb));
        h[3] = __int_as_float(__builtin_amdgcn_ds_bpermute(a3, hb));
        h[4] = __int_as_float(__builtin_amdgcn_ds_bpermute(a4, hb));
    }
}

__global__ void __launch_bounds__(64, 2) gru_all(
    const float* __restrict__ x,
    const float* __restrict__ wih0, const float* __restrict__ whh0,
    const float* __restrict__ bih0, const float* __restrict__ bhh0,
    const float* __restrict__ wihL, const float* __restrict__ whhL,
    const float* __restrict__ bihL, const float* __restrict__ bhhL,
    float* __restrict__ out)
{
    __shared__ __align__(16) float buf[2][T][6][12];

    const int lane = threadIdx.x;
    const int le = lane < 60 ? lane : 59;   // phantom lanes duplicate lane 59
    const int e = le / 10;
    const int r10 = le - e * 10;
    const int d = r10 / 5;
    const int j = r10 - d * 5;
    long b = (long)blockIdx.x * 6 + e;
    if (b >= NB) b = NB - 1;

    const int Lb = (e * 10 + d * 5) * 4;    // bpermute byte addrs for h gather
    const int a0 = Lb, a1 = Lb + 4, a2 = Lb + 8, a3 = Lb + 12, a4 = Lb + 16;

    // stage x (layer-0 input, 1 channel) into buf[0][t][e][0]
    for (int f = lane; f < 6 * T; f += 64) {
        int ee = f / T, tt = f - ee * T;
        long bb = (long)blockIdx.x * 6 + ee;
        if (bb >= NB) bb = NB - 1;
        buf[0][tt][ee][0] = x[bb * T + tt];
    }
    __syncthreads();

    // layer 0: input dim 1
    gru_layer<1>(wih0 + d * 15, whh0 + d * 75, bih0 + d * 15, bhh0 + d * 15,
                 buf[0], buf[1], e, d, j, a0, a1, a2, a3, a4);
    __syncthreads();

    int cur = 1;
    for (int l = 1; l < 5; l++) {
        const int od = (l - 1) * 2 + d;
        gru_layer<10>(wihL + od * 150, whhL + od * 75, bihL + od * 15, bhhL + od * 15,
                      buf[cur], buf[cur ^ 1], e, d, j, a0, a1, a2, a3, a4);
        cur ^= 1;
        __syncthreads();
    }

    // final output: layer-4 ys[T-1], channels [fwd(5) | bwd(5)]
    out[b * 10 + 5 * d + j] = buf[cur][T - 1][e][5 * d + j];
}

extern "C" void kernel_launch(void* const* d_in, const int* in_sizes, int n_in,
                              void* d_out, int out_size, void* d_ws, size_t ws_size,
                              hipStream_t stream) {
    const float* x    = (const float*)d_in[0];
    const float* wih0 = (const float*)d_in[1];
    const float* whh0 = (const float*)d_in[2];
    const float* bih0 = (const float*)d_in[3];
    const float* bhh0 = (const float*)d_in[4];
    const float* wihL = (const float*)d_in[5];
    const float* whhL = (const float*)d_in[6];
    const float* bihL = (const float*)d_in[7];
    const float* bhhL = (const float*)d_in[8];
    float* out = (float*)d_out;

    const int blocks = (NB + 5) / 6;   // 6 batch elements per 64-lane wave
    gru_all<<<blocks, 64, 0, stream>>>(x, wih0, whh0, bih0, bhh0,
                                       wihL, whhL, bihL, bhhL, out);
}

// Round 2
// 696.656 us; speedup vs baseline: 1.2372x; 1.2372x over previous
//
#include <hip/hip_runtime.h>

// Fully-fused 5-layer bidirectional GRU.
// 10 lanes per batch element = 2 dirs x 5 hidden units; 6 elems / wave;
// 1 wave / block. Recurrent h in fp32 (ds_bpermute all-gather each step);
// inter-layer sequences stored in LDS as f16 pairs and consumed with
// v_dot2_f32_f16 (fp32 accumulate). Activation scale factors (-log2e for
// r/z, 2*log2e for n) are folded into the weights/biases at layer start.
// Layer 4 skips LDS entirely: only ys[T-1] is needed -> fwd stores at its
// last step, bwd at its first step, fp32 direct to global.
// LDS: x stage 720 B + 2 x [T][6][6] half2 seq = 9360 B -> ~17 blocks/CU.

#define NB 262144
#define T 30

typedef _Float16 h2 __attribute__((ext_vector_type(2)));

#define SIG_SCALE  (-1.4426950408889634f)   // -log2(e)
#define TANH_SCALE ( 2.8853900817779268f)   // 2*log2(e)

#if defined(__has_builtin)
#if __has_builtin(__builtin_amdgcn_fdot2)
#define HAVE_FDOT2 1
#endif
#endif

__device__ __forceinline__ float fdot2f(h2 a, h2 b, float c) {
#ifdef HAVE_FDOT2
    return __builtin_amdgcn_fdot2(a, b, c, false);
#else
    return fmaf((float)a.x, (float)b.x, fmaf((float)a.y, (float)b.y, c));
#endif
}

// x pre-scaled by -log2e:  sigmoid(orig) = 1/(1+2^x)
__device__ __forceinline__ float sig_s(float xs) {
    return __builtin_amdgcn_rcpf(1.0f + __builtin_amdgcn_exp2f(xs));
}
// x pre-scaled by 2*log2e: tanh(orig) = 1 - 2/(1+2^x)
__device__ __forceinline__ float tanh_s(float xs) {
    return fmaf(-2.0f, __builtin_amdgcn_rcpf(1.0f + __builtin_amdgcn_exp2f(xs)), 1.0f);
}

#define GATHER_H()                                                        \
    do {                                                                  \
        int hb = __float_as_int(hme);                                     \
        h[0] = __int_as_float(__builtin_amdgcn_ds_bpermute(a0, hb));      \
        h[1] = __int_as_float(__builtin_amdgcn_ds_bpermute(a1, hb));      \
        h[2] = __int_as_float(__builtin_amdgcn_ds_bpermute(a2, hb));      \
        h[3] = __int_as_float(__builtin_amdgcn_ds_bpermute(a3, hb));      \
        h[4] = __int_as_float(__builtin_amdgcn_ds_bpermute(a4, hb));      \
    } while (0)

// layer 0: input dim 1, fp32 x from LDS, writes f16 seq
__device__ __forceinline__ void layer0(
    const float* __restrict__ wih, const float* __restrict__ whh,
    const float* __restrict__ bih, const float* __restrict__ bhh,
    const float* xbase, _Float16* outbase,
    int e, int d, int j, int c, int a0, int a1, int a2, int a3, int a4)
{
    const float wr = SIG_SCALE * wih[j];
    const float wz = SIG_SCALE * wih[j + 5];
    const float wn = TANH_SCALE * wih[j + 10];
    float wh0[5], wh1[5], wh2[5];
#pragma unroll
    for (int k = 0; k < 5; k++) {
        wh0[k] = SIG_SCALE * whh[j * 5 + k];
        wh1[k] = SIG_SCALE * whh[(j + 5) * 5 + k];
        wh2[k] = TANH_SCALE * whh[(j + 10) * 5 + k];
    }
    const float br  = SIG_SCALE * (bih[j] + bhh[j]);
    const float bz  = SIG_SCALE * (bih[j + 5] + bhh[j + 5]);
    const float bni = TANH_SCALE * bih[j + 10];
    const float bnh = TANH_SCALE * bhh[j + 10];

    float h[5] = {0.f, 0.f, 0.f, 0.f, 0.f}, hme = 0.f;
    const float* xp = xbase + (d ? (T - 1) * 6 : 0) + e;
    _Float16* wp = outbase + (d ? (T - 1) * 72 : 0) + e * 12 + c;
    const int xstep = d ? -6 : 6;
    const int wstep = d ? -72 : 72;

    for (int t = 0; t < T; t++) {
        float xv = *xp;
        float ar = fmaf(wr, xv, br);
        float az = fmaf(wz, xv, bz);
        float an = fmaf(wn, xv, bni);
        float ah = bnh;
#pragma unroll
        for (int k = 0; k < 5; k++) {
            ar = fmaf(wh0[k], h[k], ar);
            az = fmaf(wh1[k], h[k], az);
            ah = fmaf(wh2[k], h[k], ah);
        }
        float r = sig_s(ar);
        float z = sig_s(az);
        float n = tanh_s(fmaf(r, ah, an));
        hme = fmaf(z, hme - n, n);
        *wp = (_Float16)hme;
        GATHER_H();
        xp += xstep;
        wp += wstep;
    }
}

// layers 1..4: input dim 10 as f16 pairs via fdot2
template <bool WRITE, bool STORE>
__device__ __forceinline__ void layerH(
    const float* __restrict__ wih, const float* __restrict__ whh,
    const float* __restrict__ bih, const float* __restrict__ bhh,
    const h2* inbase, _Float16* outbase, float* outg,
    int e, int d, int j, int c, int a0, int a1, int a2, int a3, int a4)
{
    h2 w0[5], w1[5], w2[5];
    float wh0[5], wh1[5], wh2[5];
#pragma unroll
    for (int k = 0; k < 5; k++) {
        w0[k] = h2{(_Float16)(SIG_SCALE * wih[j * 10 + 2 * k]),
                   (_Float16)(SIG_SCALE * wih[j * 10 + 2 * k + 1])};
        w1[k] = h2{(_Float16)(SIG_SCALE * wih[(j + 5) * 10 + 2 * k]),
                   (_Float16)(SIG_SCALE * wih[(j + 5) * 10 + 2 * k + 1])};
        w2[k] = h2{(_Float16)(TANH_SCALE * wih[(j + 10) * 10 + 2 * k]),
                   (_Float16)(TANH_SCALE * wih[(j + 10) * 10 + 2 * k + 1])};
        wh0[k] = SIG_SCALE * whh[j * 5 + k];
        wh1[k] = SIG_SCALE * whh[(j + 5) * 5 + k];
        wh2[k] = TANH_SCALE * whh[(j + 10) * 5 + k];
    }
    const float br  = SIG_SCALE * (bih[j] + bhh[j]);
    const float bz  = SIG_SCALE * (bih[j + 5] + bhh[j + 5]);
    const float bni = TANH_SCALE * bih[j + 10];
    const float bnh = TANH_SCALE * bhh[j + 10];

    float h[5] = {0.f, 0.f, 0.f, 0.f, 0.f}, hme = 0.f;
    const h2* xp = inbase + (d ? (T - 1) * 36 : 0) + e * 6;
    _Float16* wp = outbase + (d ? (T - 1) * 72 : 0) + e * 12 + c;
    const int xstep = d ? -36 : 36;
    const int wstep = d ? -72 : 72;
    const int tout = d ? 0 : T - 1;

    for (int t = 0; t < T; t++) {
        h2 x0 = xp[0], x1 = xp[1], x2 = xp[2], x3 = xp[3], x4 = xp[4];
        float ar = br, az = bz, an = bni, ah = bnh;
        ar = fdot2f(w0[0], x0, ar); ar = fdot2f(w0[1], x1, ar);
        ar = fdot2f(w0[2], x2, ar); ar = fdot2f(w0[3], x3, ar);
        ar = fdot2f(w0[4], x4, ar);
        az = fdot2f(w1[0], x0, az); az = fdot2f(w1[1], x1, az);
        az = fdot2f(w1[2], x2, az); az = fdot2f(w1[3], x3, az);
        az = fdot2f(w1[4], x4, az);
        an = fdot2f(w2[0], x0, an); an = fdot2f(w2[1], x1, an);
        an = fdot2f(w2[2], x2, an); an = fdot2f(w2[3], x3, an);
        an = fdot2f(w2[4], x4, an);
#pragma unroll
        for (int k = 0; k < 5; k++) {
            ar = fmaf(wh0[k], h[k], ar);
            az = fmaf(wh1[k], h[k], az);
            ah = fmaf(wh2[k], h[k], ah);
        }
        float r = sig_s(ar);
        float z = sig_s(az);
        float n = tanh_s(fmaf(r, ah, an));
        hme = fmaf(z, hme - n, n);
        if (WRITE) *wp = (_Float16)hme;
        if (STORE) { if (t == tout) *outg = hme; }
        GATHER_H();
        xp += xstep;
        if (WRITE) wp += wstep;
    }
}

__global__ void __launch_bounds__(64, 4) gru_all(
    const float* __restrict__ x,
    const float* __restrict__ wih0, const float* __restrict__ whh0,
    const float* __restrict__ bih0, const float* __restrict__ bhh0,
    const float* __restrict__ wihL, const float* __restrict__ whhL,
    const float* __restrict__ bihL, const float* __restrict__ bhhL,
    float* __restrict__ out)
{
    __shared__ __align__(16) float xbuf[T][6];
    __shared__ __align__(16) h2 seq[2][T][6][6];   // f16 pairs: ch (01)(23)(45)(67)(89)+pad

    const int lane = threadIdx.x;
    const int le = lane < 60 ? lane : 59;   // phantom lanes duplicate lane 59
    const int e = le / 10;
    const int r10 = le - e * 10;
    const int d = r10 / 5;
    const int j = r10 - d * 5;
    const int c = 5 * d + j;
    long b = (long)blockIdx.x * 6 + e;
    if (b >= NB) b = NB - 1;

    const int Lb = (e * 10 + d * 5) * 4;
    const int a0 = Lb, a1 = Lb + 4, a2 = Lb + 8, a3 = Lb + 12, a4 = Lb + 16;

    for (int f = lane; f < 6 * T; f += 64) {
        int ee = f / T, tt = f - ee * T;
        long bb = (long)blockIdx.x * 6 + ee;
        if (bb >= NB) bb = NB - 1;
        xbuf[tt][ee] = x[bb * T + tt];
    }
    __syncthreads();

    layer0(wih0 + d * 15, whh0 + d * 75, bih0 + d * 15, bhh0 + d * 15,
           &xbuf[0][0], (_Float16*)&seq[0][0][0][0],
           e, d, j, c, a0, a1, a2, a3, a4);
    __syncthreads();

    int cur = 0;
    for (int l = 1; l < 4; l++) {
        const int od = (l - 1) * 2 + d;
        layerH<true, false>(wihL + od * 150, whhL + od * 75,
                            bihL + od * 15, bhhL + od * 15,
                            &seq[cur][0][0][0], (_Float16*)&seq[cur ^ 1][0][0][0], nullptr,
                            e, d, j, c, a0, a1, a2, a3, a4);
        cur ^= 1;
        __syncthreads();
    }

    // layer 4: no LDS output; fwd stores at t=T-1, bwd at t=0 (== ys[T-1])
    {
        const int od = 3 * 2 + d;
        layerH<false, true>(wihL + od * 150, whhL + od * 75,
                            bihL + od * 15, bhhL + od * 15,
                            &seq[cur][0][0][0], nullptr, out + b * 10 + c,
                            e, d, j, c, a0, a1, a2, a3, a4);
    }
}

extern "C" void kernel_launch(void* const* d_in, const int* in_sizes, int n_in,
                              void* d_out, int out_size, void* d_ws, size_t ws_size,
                              hipStream_t stream) {
    const float* x    = (const float*)d_in[0];
    const float* wih0 = (const float*)d_in[1];
    const float* whh0 = (const float*)d_in[2];
    const float* bih0 = (const float*)d_in[3];
    const float* bhh0 = (const float*)d_in[4];
    const float* wihL = (const float*)d_in[5];
    const float* whhL = (const float*)d_in[6];
    const float* bihL = (const float*)d_in[7];
    const float* bhhL = (const float*)d_in[8];
    float* out = (float*)d_out;

    const int blocks = (NB + 5) / 6;   // 6 batch elements per 64-lane wave
    gru_all<<<blocks, 64, 0, stream>>>(x, wih0, whh0, bih0, bhh0,
                                       wihL, whhL, bihL, bhhL, out);
}